// Round 5
// baseline (467.603 us; speedup 1.0000x reference)
//
#include <hip/hip_runtime.h>
#include <cstdint>
#include <cstddef>

typedef unsigned short u16;
typedef unsigned int   u32;
typedef unsigned long long u64;
typedef __attribute__((ext_vector_type(8))) short short8;   // 8 bf16 = 4 VGPR
typedef __attribute__((ext_vector_type(4))) float f32x4;

#define M_ROWS 16384
#define N_COLS 256
#define IN_F   1024
#define K_SPL  8192   // 1024 features * 8 basis
#define K_TOT  9216   // + 1024 base (silu) features
// BK=64 chunks: 144 total (128 spline chunks of 8 features, 16 base chunks of 64 feats)
#define NCHUNK 144
#define SPLITK 2
#define CPB    (NCHUNK / SPLITK)   // 72 chunks per block

// ---------- helpers ----------
__device__ __forceinline__ u32 f2bf1(float f) {          // f32 -> bf16 bits, RNE
  u32 u = __float_as_uint(f);
  u += 0x7fffu + ((u >> 16) & 1u);
  return u >> 16;
}
__device__ __forceinline__ u32 pk2(float a, float b) {
  return f2bf1(a) | (f2bf1(b) << 16);
}
__device__ __forceinline__ float silu(float v) {
  return v * __builtin_amdgcn_rcpf(1.f + __expf(-v));
}

// 8 bf16 cubic B-spline basis values for one x, packed as uint4 (16B).
// u = 2.5x + 5.5; basis_j(x) = N3(u - j); 4 nonzero wts scattered via funnel shift.
__device__ __forceinline__ uint4 basis8(float xv) {
  float u = fmaf(xv, 2.5f, 5.5f);
  int i0 = (int)u;
  float fr = u - (float)i0;
  float fr2 = fr * fr, fr3 = fr2 * fr;
  float om  = 1.f - fr;
  float om3 = om * om * om;
  float w0 = om3 * (1.f / 6.f);
  float w3 = fr3 * (1.f / 6.f);
  float w1 = fmaf(fr3, 0.5f, fmaf(fr2, -1.f, 2.f / 3.f));
  float w2 = fmaf(fr + fr2 - fr3, 0.5f, 1.f / 6.f);
  u64 W = (u64)pk2(w0, w1) | ((u64)pk2(w2, w3) << 32);
  if (!(u >= 0.f && u < 11.f)) W = 0ull;
  int s = (i0 - 3) * 16;
  u64 lo, hi;
  if (s >= 64)      { int r = s - 64; lo = 0ull; hi = (r < 64) ? (W << r) : 0ull; }
  else if (s > 0)   { lo = W << s;    hi = W >> (64 - s); }
  else if (s == 0)  { lo = W;         hi = 0ull; }
  else              { int r = -s;     lo = (r < 64) ? (W >> r) : 0ull; hi = 0ull; }
  uint4 o;
  o.x = (u32)lo; o.y = (u32)(lo >> 32); o.z = (u32)hi; o.w = (u32)(hi >> 32);
  return o;
}

// ---------- kernel 1: pack [spline_weight | base_weight] -> bf16, (256 x 9216) row-major ----------
__global__ void pack_weights(const float* __restrict__ bw, const float* __restrict__ sw,
                             u16* __restrict__ Bp) {
  int o  = blockIdx.y;
  int k4 = (blockIdx.x * blockDim.x + threadIdx.x) * 4;
  const float* src = (k4 < K_SPL) ? (sw + (size_t)o * K_SPL + k4)
                                  : (bw + (size_t)o * IN_F + (k4 - K_SPL));
  float a = src[0], b = src[1], c = src[2], d = src[3];
  uint2 v; v.x = pk2(a, b); v.y = pk2(c, d);
  *(uint2*)(Bp + (size_t)o * K_TOT + k4) = v;
}

// ---------- kernel 2: fused KAN GEMM ----------
// R5 theory: R4 ran at ~90% of LDS read BW (320KB reads/chunk/CU; 28.8MB/CU
// total = 107us floor vs 120 measured) -> LDS-BANDWIDTH-bound, not latency.
// Fix: regrid 16 waves as 2(m:32rows) x 4(n:64cols) x 2(k-half). Each wave
// owns a 32x64 output tile and ONE 32-wide k-half of each BK=64 chunk:
// 6 ds_read_b128 (2A+4B) per 8 MFMAs instead of 10 -> block LDS traffic
// 160->96 KB/chunk (B amplification 4x->2x). New floor ~73us.
// k-half partial sums are merged through the SAME atomic epilogue as split-K
// (out=16MB is L2-resident; 4 temporally-clustered RMWs/line - not R2's
// thrash pattern). acc 2x4 = 32 VGPR; target <=64 (R1 compiled this frag
// shape at 52). Everything else (traffic shape, swizzle, dbuf 1-barrier loop,
// bgrp build rotation, launch geometry 512x1024) identical to R4.
__global__ __launch_bounds__(1024, 8)
void kan_gemm(const float* __restrict__ x, const u16* __restrict__ Bp,
              float* __restrict__ out) {
  __shared__ __align__(16) u16 Bs[2 * 256 * 64];   // 64 KB (2 bufs)
  __shared__ __align__(16) u16 As[2 * 64 * 64];    // 16 KB (2 bufs)

  const int tid  = threadIdx.x;
  const int lane = tid & 63;
  const int w    = tid >> 6;          // 0..15
  const int kh   = w & 1;             // k-half of the BK=64 chunk (0: k<32, 1: k>=32)
  const int wm   = (w >> 1) & 1;      // m-half (32 rows)
  const int wn   = w >> 2;            // n-quarter (64 cols)

  const int bid  = blockIdx.x;        // 512
  const int kid  = bid & 1;           // adjacent split-K partners (R0-proven)
  const int mb   = bid >> 1;          // 0..255
  const int row0 = mb * 64;
  const int cs   = kid * CPB, c1 = cs + CPB;   // cs even (CPB=72)

  f32x4 acc[2][4];
#pragma unroll
  for (int i = 0; i < 2; ++i)
#pragma unroll
    for (int j = 0; j < 4; ++j)
      acc[i][j] = (f32x4){0.f, 0.f, 0.f, 0.f};

  // builder mapping: 512 builds/chunk (64 rows x 8 feat-chunks); thread-half
  // bgrp builds chunks with (c&1)==bgrp.
  const int sr   = (tid >> 3) & 63;   // row 0..63
  const int sq   = tid & 7;           // 16B feature-chunk 0..7
  const int bgrp = tid >> 9;          // 0 or 1

  // fragment read offsets (u16 index within one buffer), swizzled.
  // 16B-chunk index within row = kh*4 + kg (kg = lane>>4 selects k = kg*8..+7
  // inside the wave's 32-wide k-window).
  const int lm = lane & 15;
  const int kg = lane >> 4;
  const int c4 = kh * 4 + kg;
  int a_off[2], b_off[4];
#pragma unroll
  for (int i = 0; i < 2; ++i) {
    int ra = wm * 32 + i * 16 + lm;
    a_off[i] = ra * 64 + ((c4 ^ (ra & 7)) * 8);
  }
#pragma unroll
  for (int j = 0; j < 4; ++j) {
    int rb = wn * 64 + j * 16 + lm;
    b_off[j] = rb * 64 + ((c4 ^ (rb & 7)) * 8);
  }

  // B staging: 1024 thr x 2 iters x 16B = 32 KB chunk; linear LDS dest,
  // inverse-swizzled global source (both-sides-or-neither rule).
  u32 stage_goff[2];
  int stage_loff[2];
#pragma unroll
  for (int it = 0; it < 2; ++it) {
    int s  = tid + it * 1024;
    int r_ = s >> 3, cc = (s & 7) ^ (r_ & 7);
    stage_goff[it] = (u32)r_ * K_TOT + cc * 8;
    stage_loff[it] = s * 8;
  }

  float px;            // spline prefetch (1 feature, active bgrp only)
  float4 pb0, pb1;     // base prefetch (8 features, active bgrp only)

  auto LOADX = [&](int c) {
    if ((c & 1) != bgrp) return;
    if (c < 128) {
      px = x[(size_t)(row0 + sr) * IN_F + c * 8 + sq];
    } else {
      const float* xp = x + (size_t)(row0 + sr) * IN_F + (c - 128) * 64 + sq * 8;
      pb0 = *(const float4*)xp;
      pb1 = *(const float4*)(xp + 4);
    }
  };

  auto BUILD = [&](int c, int buf) {
    if ((c & 1) != bgrp) return;
    uint4 q;
    if (c < 128) {
      q = basis8(px);
    } else {
      q.x = pk2(silu(pb0.x), silu(pb0.y));
      q.y = pk2(silu(pb0.z), silu(pb0.w));
      q.z = pk2(silu(pb1.x), silu(pb1.y));
      q.w = pk2(silu(pb1.z), silu(pb1.w));
    }
    *(uint4*)(As + buf * (64 * 64) + sr * 64 + ((sq ^ (sr & 7)) * 8)) = q;
  };

  auto STAGEB = [&](int c, int buf) {
    u16* base = Bs + buf * (256 * 64);
#pragma unroll
    for (int it = 0; it < 2; ++it) {
      const u16* gp = Bp + stage_goff[it] + c * 64;
      __builtin_amdgcn_global_load_lds((const __attribute__((address_space(1))) void*)gp,
                                       (__attribute__((address_space(3))) void*)(base + stage_loff[it]),
                                       16, 0, 0);
    }
  };

  auto MFMA_PHASE = [&](int buf) {
    const u16* Ab = As + buf * (64 * 64);
    const u16* Bb = Bs + buf * (256 * 64);
    short8 af[2], bf[4];
#pragma unroll
    for (int i = 0; i < 2; ++i) af[i] = *(const short8*)(Ab + a_off[i]);
#pragma unroll
    for (int j = 0; j < 4; ++j) bf[j] = *(const short8*)(Bb + b_off[j]);
#pragma unroll
    for (int i = 0; i < 2; ++i)
#pragma unroll
      for (int j = 0; j < 4; ++j)
        acc[i][j] = __builtin_amdgcn_mfma_f32_16x16x32_bf16(af[i], bf[j], acc[i][j], 0, 0, 0);
  };

  // ---- prologue: chunk cs -> buf 0 ----
  LOADX(cs);
  STAGEB(cs, 0);
  BUILD(cs, 0);
  if (cs + 1 < c1) LOADX(cs + 1);
  __syncthreads();   // buf0 ready

  // ---- main loop: 1 barrier per chunk, x2 unrolled for static buffer idx ----
  for (int c = cs; c < c1; c += 2) {
    // chunk c on buf0; prefetch chunk c+1 -> buf1
    if (c + 1 < c1) { STAGEB(c + 1, 1); BUILD(c + 1, 1); }
    if (c + 2 < c1) LOADX(c + 2);
    MFMA_PHASE(0);
    __syncthreads();

    // chunk c+1 on buf1; prefetch chunk c+2 -> buf0
    if (c + 1 < c1) {
      if (c + 2 < c1) { STAGEB(c + 2, 0); BUILD(c + 2, 0); }
      if (c + 3 < c1) LOADX(c + 3);
      MFMA_PHASE(1);
      __syncthreads();
    }
  }

  // ---- epilogue: C/D layout col=lane&15, row=(lane>>4)*4+reg ----
  // split-K=2 AND k-half split -> 4 atomic adds per out element, temporally
  // clustered; out (16MB) is L2-resident so extra RMWs stay on-die.
  const int lc = lane & 15;
  const int lr = (lane >> 4) * 4;
#pragma unroll
  for (int i = 0; i < 2; ++i) {
#pragma unroll
    for (int j = 0; j < 4; ++j) {
      int gr = row0 + wm * 32 + i * 16 + lr;
      int gc = wn * 64 + j * 16 + lc;
      float* po = out + (size_t)gr * N_COLS + gc;
#pragma unroll
      for (int r = 0; r < 4; ++r)
        unsafeAtomicAdd(po + (size_t)r * N_COLS, acc[i][j][r]);
    }
  }
}

extern "C" void kernel_launch(void* const* d_in, const int* in_sizes, int n_in,
                              void* d_out, int out_size, void* d_ws, size_t ws_size,
                              hipStream_t stream) {
  const float* x  = (const float*)d_in[0];   // 16384 x 1024
  const float* bw = (const float*)d_in[1];   // 256 x 1024
  const float* sw = (const float*)d_in[2];   // 256 x 8192
  float* out = (float*)d_out;                // 16384 x 256 f32
  u16* Bp = (u16*)d_ws;                      // 256 x 9216 bf16 = 4.5 MB

  hipMemsetAsync(d_out, 0, (size_t)M_ROWS * N_COLS * sizeof(float), stream);

  dim3 pgrid(K_TOT / 4 / 256, N_COLS);       // (9, 256)
  pack_weights<<<pgrid, 256, 0, stream>>>(bw, sw, Bp);

  kan_gemm<<<512, 1024, 0, stream>>>(x, Bp, out);
}

// Round 6
// 453.618 us; speedup vs baseline: 1.0308x; 1.0308x over previous
//
#include <hip/hip_runtime.h>
#include <cstdint>
#include <cstddef>

typedef unsigned short u16;
typedef unsigned int   u32;
typedef unsigned long long u64;
typedef __attribute__((ext_vector_type(8))) short short8;   // 8 bf16 = 4 VGPR
typedef __attribute__((ext_vector_type(4))) float f32x4;

#define M_ROWS 16384
#define N_COLS 256
#define IN_F   1024
#define K_SPL  8192   // 1024 features * 8 basis
#define K_TOT  9216   // + 1024 base (silu) features
// BK=64 chunks: 144 total (128 spline chunks of 8 features, 16 base chunks of 64 feats)
#define NCHUNK 144
#define SPLITK 2
#define CPB    (NCHUNK / SPLITK)   // 72 chunks per block

// ---------- helpers ----------
__device__ __forceinline__ u32 f2bf1(float f) {          // f32 -> bf16 bits, RNE
  u32 u = __float_as_uint(f);
  u += 0x7fffu + ((u >> 16) & 1u);
  return u >> 16;
}
__device__ __forceinline__ u32 pk2(float a, float b) {
  return f2bf1(a) | (f2bf1(b) << 16);
}
__device__ __forceinline__ float silu(float v) {
  return v * __builtin_amdgcn_rcpf(1.f + __expf(-v));
}

// 8 bf16 cubic B-spline basis values for one x, packed as uint4 (16B).
// u = 2.5x + 5.5; basis_j(x) = N3(u - j); 4 nonzero wts scattered via funnel shift.
__device__ __forceinline__ uint4 basis8(float xv) {
  float u = fmaf(xv, 2.5f, 5.5f);
  int i0 = (int)u;
  float fr = u - (float)i0;
  float fr2 = fr * fr, fr3 = fr2 * fr;
  float om  = 1.f - fr;
  float om3 = om * om * om;
  float w0 = om3 * (1.f / 6.f);
  float w3 = fr3 * (1.f / 6.f);
  float w1 = fmaf(fr3, 0.5f, fmaf(fr2, -1.f, 2.f / 3.f));
  float w2 = fmaf(fr + fr2 - fr3, 0.5f, 1.f / 6.f);
  u64 W = (u64)pk2(w0, w1) | ((u64)pk2(w2, w3) << 32);
  if (!(u >= 0.f && u < 11.f)) W = 0ull;
  int s = (i0 - 3) * 16;
  u64 lo, hi;
  if (s >= 64)      { int r = s - 64; lo = 0ull; hi = (r < 64) ? (W << r) : 0ull; }
  else if (s > 0)   { lo = W << s;    hi = W >> (64 - s); }
  else if (s == 0)  { lo = W;         hi = 0ull; }
  else              { int r = -s;     lo = (r < 64) ? (W >> r) : 0ull; hi = 0ull; }
  uint4 o;
  o.x = (u32)lo; o.y = (u32)(lo >> 32); o.z = (u32)hi; o.w = (u32)(hi >> 32);
  return o;
}

// ---------- kernel 1: pack [spline_weight | base_weight] -> bf16, (256 x 9216) row-major ----------
__global__ void pack_weights(const float* __restrict__ bw, const float* __restrict__ sw,
                             u16* __restrict__ Bp) {
  int o  = blockIdx.y;
  int k4 = (blockIdx.x * blockDim.x + threadIdx.x) * 4;
  const float* src = (k4 < K_SPL) ? (sw + (size_t)o * K_SPL + k4)
                                  : (bw + (size_t)o * IN_F + (k4 - K_SPL));
  float a = src[0], b = src[1], c = src[2], d = src[3];
  uint2 v; v.x = pk2(a, b); v.y = pk2(c, d);
  *(uint2*)(Bp + (size_t)o * K_TOT + k4) = v;
}

// ---------- kernel 2: fused KAN GEMM ----------
// R6: R5 proved the k-half regrid is numerically right but its 4-atomics/elem
// epilogue exploded HBM (WRITE 731MB, FETCH 506MB; R2 measured same rule:
// >=4 atomic writers/line goes ~20x nonlinear; 2 writers = benign 2x out).
// Fix: keep the k-half split (2m x 4n x 2kh waves; 6 ds_read_b128 per 8
// MFMAs; block LDS reads 160->96 KB/chunk vs R4's ~90%-of-LDS-BW ceiling)
// but merge kh partials IN-BLOCK via LDS: after the final barrier, kh=1
// waves write acc (32 f32/lane) into Bs reinterpreted as f32 scratch
// (8 waves x 2048 f32 = 64 KB exactly; layout idx*512+pair*64+lane -> 2-way
// bank alias = free), barrier, kh=0 waves add and do the R4-proven
// split-K=2 atomic epilogue alone (2 writers/line).
// Everything else identical to R4/R5: BM=64 BN=256 BK=64, split-K=2 adjacent
// partners, 1024 thr = 16 waves, LDS 80KB -> 2 blocks/CU = 32 waves/CU,
// dbuf 1-barrier loop, bgrp build rotation, 16B-chunk XOR swizzle.
__global__ __launch_bounds__(1024, 8)
void kan_gemm(const float* __restrict__ x, const u16* __restrict__ Bp,
              float* __restrict__ out) {
  __shared__ __align__(16) u16 Bs[2 * 256 * 64];   // 64 KB (2 bufs) / f32 scratch in epilogue
  __shared__ __align__(16) u16 As[2 * 64 * 64];    // 16 KB (2 bufs)

  const int tid  = threadIdx.x;
  const int lane = tid & 63;
  const int w    = tid >> 6;          // 0..15
  const int kh   = w & 1;             // k-half of the BK=64 chunk (0: k<32, 1: k>=32)
  const int wm   = (w >> 1) & 1;      // m-half (32 rows)
  const int wn   = w >> 2;            // n-quarter (64 cols)
  const int wp   = w >> 1;            // (wm,wn) pair id 0..7

  const int bid  = blockIdx.x;        // 512
  const int kid  = bid & 1;           // adjacent split-K partners (R0-proven)
  const int mb   = bid >> 1;          // 0..255
  const int row0 = mb * 64;
  const int cs   = kid * CPB, c1 = cs + CPB;   // cs even (CPB=72)

  f32x4 acc[2][4];
#pragma unroll
  for (int i = 0; i < 2; ++i)
#pragma unroll
    for (int j = 0; j < 4; ++j)
      acc[i][j] = (f32x4){0.f, 0.f, 0.f, 0.f};

  // builder mapping: 512 builds/chunk (64 rows x 8 feat-chunks); thread-half
  // bgrp builds chunks with (c&1)==bgrp.
  const int sr   = (tid >> 3) & 63;   // row 0..63
  const int sq   = tid & 7;           // 16B feature-chunk 0..7
  const int bgrp = tid >> 9;          // 0 or 1

  // fragment read offsets (u16 index within one buffer), swizzled.
  // 16B-chunk index within row = kh*4 + kg (kg = lane>>4 selects k = kg*8..+7
  // inside the wave's 32-wide k-window).
  const int lm = lane & 15;
  const int kg = lane >> 4;
  const int c4 = kh * 4 + kg;
  int a_off[2], b_off[4];
#pragma unroll
  for (int i = 0; i < 2; ++i) {
    int ra = wm * 32 + i * 16 + lm;
    a_off[i] = ra * 64 + ((c4 ^ (ra & 7)) * 8);
  }
#pragma unroll
  for (int j = 0; j < 4; ++j) {
    int rb = wn * 64 + j * 16 + lm;
    b_off[j] = rb * 64 + ((c4 ^ (rb & 7)) * 8);
  }

  // B staging: 1024 thr x 2 iters x 16B = 32 KB chunk; linear LDS dest,
  // inverse-swizzled global source (both-sides-or-neither rule).
  u32 stage_goff[2];
  int stage_loff[2];
#pragma unroll
  for (int it = 0; it < 2; ++it) {
    int s  = tid + it * 1024;
    int r_ = s >> 3, cc = (s & 7) ^ (r_ & 7);
    stage_goff[it] = (u32)r_ * K_TOT + cc * 8;
    stage_loff[it] = s * 8;
  }

  float px;            // spline prefetch (1 feature, active bgrp only)
  float4 pb0, pb1;     // base prefetch (8 features, active bgrp only)

  auto LOADX = [&](int c) {
    if ((c & 1) != bgrp) return;
    if (c < 128) {
      px = x[(size_t)(row0 + sr) * IN_F + c * 8 + sq];
    } else {
      const float* xp = x + (size_t)(row0 + sr) * IN_F + (c - 128) * 64 + sq * 8;
      pb0 = *(const float4*)xp;
      pb1 = *(const float4*)(xp + 4);
    }
  };

  auto BUILD = [&](int c, int buf) {
    if ((c & 1) != bgrp) return;
    uint4 q;
    if (c < 128) {
      q = basis8(px);
    } else {
      q.x = pk2(silu(pb0.x), silu(pb0.y));
      q.y = pk2(silu(pb0.z), silu(pb0.w));
      q.z = pk2(silu(pb1.x), silu(pb1.y));
      q.w = pk2(silu(pb1.z), silu(pb1.w));
    }
    *(uint4*)(As + buf * (64 * 64) + sr * 64 + ((sq ^ (sr & 7)) * 8)) = q;
  };

  auto STAGEB = [&](int c, int buf) {
    u16* base = Bs + buf * (256 * 64);
#pragma unroll
    for (int it = 0; it < 2; ++it) {
      const u16* gp = Bp + stage_goff[it] + c * 64;
      __builtin_amdgcn_global_load_lds((const __attribute__((address_space(1))) void*)gp,
                                       (__attribute__((address_space(3))) void*)(base + stage_loff[it]),
                                       16, 0, 0);
    }
  };

  auto MFMA_PHASE = [&](int buf) {
    const u16* Ab = As + buf * (64 * 64);
    const u16* Bb = Bs + buf * (256 * 64);
    short8 af[2], bf[4];
#pragma unroll
    for (int i = 0; i < 2; ++i) af[i] = *(const short8*)(Ab + a_off[i]);
#pragma unroll
    for (int j = 0; j < 4; ++j) bf[j] = *(const short8*)(Bb + b_off[j]);
#pragma unroll
    for (int i = 0; i < 2; ++i)
#pragma unroll
      for (int j = 0; j < 4; ++j)
        acc[i][j] = __builtin_amdgcn_mfma_f32_16x16x32_bf16(af[i], bf[j], acc[i][j], 0, 0, 0);
  };

  // ---- prologue: chunk cs -> buf 0 ----
  LOADX(cs);
  STAGEB(cs, 0);
  BUILD(cs, 0);
  if (cs + 1 < c1) LOADX(cs + 1);
  __syncthreads();   // buf0 ready

  // ---- main loop: 1 barrier per chunk, x2 unrolled for static buffer idx ----
  for (int c = cs; c < c1; c += 2) {
    // chunk c on buf0; prefetch chunk c+1 -> buf1
    if (c + 1 < c1) { STAGEB(c + 1, 1); BUILD(c + 1, 1); }
    if (c + 2 < c1) LOADX(c + 2);
    MFMA_PHASE(0);
    __syncthreads();

    // chunk c+1 on buf1; prefetch chunk c+2 -> buf0
    if (c + 1 < c1) {
      if (c + 2 < c1) { STAGEB(c + 2, 0); BUILD(c + 2, 0); }
      if (c + 3 < c1) LOADX(c + 3);
      MFMA_PHASE(1);
      __syncthreads();
    }
  }
  // loop ends with __syncthreads(): all ds_reads of Bs complete -> safe to reuse

  // ---- kh-merge through LDS: kh=1 waves dump, kh=0 waves accumulate ----
  float* Ls = (float*)Bs;     // 64 KB scratch = 8 pairs x 2048 f32
  if (kh) {
#pragma unroll
    for (int i = 0; i < 2; ++i)
#pragma unroll
      for (int j = 0; j < 4; ++j)
#pragma unroll
        for (int r = 0; r < 4; ++r)
          Ls[((i * 4 + j) * 4 + r) * 512 + wp * 64 + lane] = acc[i][j][r];
  }
  __syncthreads();

  // ---- epilogue (kh=0 waves only): C/D layout col=lane&15, row=(lane>>4)*4+reg;
  // split-K=2 -> exactly 2 atomic writers per line (R4-proven benign) ----
  if (!kh) {
    const int lc = lane & 15;
    const int lr = (lane >> 4) * 4;
#pragma unroll
    for (int i = 0; i < 2; ++i) {
#pragma unroll
      for (int j = 0; j < 4; ++j) {
        int gr = row0 + wm * 32 + i * 16 + lr;
        int gc = wn * 64 + j * 16 + lc;
        float* po = out + (size_t)gr * N_COLS + gc;
#pragma unroll
        for (int r = 0; r < 4; ++r) {
          float v = acc[i][j][r] + Ls[((i * 4 + j) * 4 + r) * 512 + wp * 64 + lane];
          unsafeAtomicAdd(po + (size_t)r * N_COLS, v);
        }
      }
    }
  }
}

extern "C" void kernel_launch(void* const* d_in, const int* in_sizes, int n_in,
                              void* d_out, int out_size, void* d_ws, size_t ws_size,
                              hipStream_t stream) {
  const float* x  = (const float*)d_in[0];   // 16384 x 1024
  const float* bw = (const float*)d_in[1];   // 256 x 1024
  const float* sw = (const float*)d_in[2];   // 256 x 8192
  float* out = (float*)d_out;                // 16384 x 256 f32
  u16* Bp = (u16*)d_ws;                      // 256 x 9216 bf16 = 4.5 MB

  hipMemsetAsync(d_out, 0, (size_t)M_ROWS * N_COLS * sizeof(float), stream);

  dim3 pgrid(K_TOT / 4 / 256, N_COLS);       // (9, 256)
  pack_weights<<<pgrid, 256, 0, stream>>>(bw, sw, Bp);

  kan_gemm<<<512, 1024, 0, stream>>>(x, Bp, out);
}

// Round 7
// 234.225 us; speedup vs baseline: 1.9964x; 1.9367x over previous
//
#include <hip/hip_runtime.h>
#include <cstdint>
#include <cstddef>

typedef unsigned short u16;
typedef unsigned int   u32;
typedef unsigned long long u64;
typedef __attribute__((ext_vector_type(8))) short short8;   // 8 bf16 = 4 VGPR
typedef __attribute__((ext_vector_type(4))) float f32x4;

#define M_ROWS 16384
#define N_COLS 256
#define IN_F   1024
#define K_SPL  8192   // 1024 features * 8 basis
#define K_TOT  9216   // + 1024 base (silu) features
// BK=32 chunks: 288 total (256 spline chunks of 4 features, 32 base chunks of 32 feats)
#define NCHUNK 288
#define SPLITK 2
#define CPB    (NCHUNK / SPLITK)   // 144 chunks per block (cs multiple of 4)

// ---------- helpers ----------
__device__ __forceinline__ u32 f2bf1(float f) {          // f32 -> bf16 bits, RNE
  u32 u = __float_as_uint(f);
  u += 0x7fffu + ((u >> 16) & 1u);
  return u >> 16;
}
__device__ __forceinline__ u32 pk2(float a, float b) {
  return f2bf1(a) | (f2bf1(b) << 16);
}
__device__ __forceinline__ float silu(float v) {
  return v * __builtin_amdgcn_rcpf(1.f + __expf(-v));
}

// 8 bf16 cubic B-spline basis values for one x, packed as uint4 (16B).
__device__ __forceinline__ uint4 basis8(float xv) {
  float u = fmaf(xv, 2.5f, 5.5f);
  int i0 = (int)u;
  float fr = u - (float)i0;
  float fr2 = fr * fr, fr3 = fr2 * fr;
  float om  = 1.f - fr;
  float om3 = om * om * om;
  float w0 = om3 * (1.f / 6.f);
  float w3 = fr3 * (1.f / 6.f);
  float w1 = fmaf(fr3, 0.5f, fmaf(fr2, -1.f, 2.f / 3.f));
  float w2 = fmaf(fr + fr2 - fr3, 0.5f, 1.f / 6.f);
  u64 W = (u64)pk2(w0, w1) | ((u64)pk2(w2, w3) << 32);
  if (!(u >= 0.f && u < 11.f)) W = 0ull;
  int s = (i0 - 3) * 16;
  u64 lo, hi;
  if (s >= 64)      { int r = s - 64; lo = 0ull; hi = (r < 64) ? (W << r) : 0ull; }
  else if (s > 0)   { lo = W << s;    hi = W >> (64 - s); }
  else if (s == 0)  { lo = W;         hi = 0ull; }
  else              { int r = -s;     lo = (r < 64) ? (W >> r) : 0ull; hi = 0ull; }
  uint4 o;
  o.x = (u32)lo; o.y = (u32)(lo >> 32); o.z = (u32)hi; o.w = (u32)(hi >> 32);
  return o;
}

// ---------- kernel 1: pack [spline_weight | base_weight] -> bf16, (256 x 9216) row-major ----------
__global__ void pack_weights(const float* __restrict__ bw, const float* __restrict__ sw,
                             u16* __restrict__ Bp) {
  int o  = blockIdx.y;
  int k4 = (blockIdx.x * blockDim.x + threadIdx.x) * 4;
  const float* src = (k4 < K_SPL) ? (sw + (size_t)o * K_SPL + k4)
                                  : (bw + (size_t)o * IN_F + (k4 - K_SPL));
  float a = src[0], b = src[1], c = src[2], d = src[3];
  uint2 v; v.x = pk2(a, b); v.y = pk2(c, d);
  *(uint2*)(Bp + (size_t)o * K_TOT + k4) = v;
}

// ---------- kernel 2: fused KAN GEMM ----------
// R7: R5/R6 post-mortem: acc[2][4]=32 VGPR under the 64-VGPR cap (8 waves/SIMD)
// SPILLED -> scratch RMW = the 500/700MB "HBM" traffic. Rule: acc <= ~16 regs
// at this occupancy. R4 (clean, 120us) had nothing saturated -> mixed
// LDS-traffic + per-chunk vmcnt(0) drain problem.
// This round (T3+T4+T5 on the R4 traffic shape):
//  * 32x32 wave tiles (16 waves = 2m x 8n): LDS bytes/MFMA 1.25->1.0 KB,
//    acc[2][2]=16 regs (no spill).
//  * BK=32, FOUR buffers (Bs 4x16KB + As 4x4KB = 80KB, still 2 blocks/CU,
//    32 waves/CU): depth-3 pipeline. Per phase: ds_read frags(c) -> issue
//    STAGEB(c+3) gl_lds -> BUILD(c+2) -> LOADX(c+3) -> s_waitcnt vmcnt(3)
//    (never 0 in steady state; guarantees chunk c+1's loads landed) +
//    lgkmcnt(0) -> raw s_barrier -> setprio(1) 4x MFMA setprio(0).
//  * builders: quarter q of the block builds chunks c%4==q (basis8 VALU
//    spread over all waves, 1 build phase in 4).
//  * split-K=2 adjacent partners, 2 atomic writers/line (R4-proven benign).
// Swizzle (BK=32, 64B rows): 16B-chunk cc of row r at slot cc ^ ((r>>1)&3)
// -> 2-way bank alias = free (R2-proven correct staging scheme).
__global__ __launch_bounds__(1024, 8)
void kan_gemm(const float* __restrict__ x, const u16* __restrict__ Bp,
              float* __restrict__ out) {
  __shared__ __align__(16) u16 Bs[4 * 256 * 32];   // 64 KB (4 bufs)
  __shared__ __align__(16) u16 As[4 * 64 * 32];    // 16 KB (4 bufs)

  const int tid  = threadIdx.x;
  const int lane = tid & 63;
  const int w    = tid >> 6;          // 0..15
  const int wm   = w & 1;             // m-half (32 rows)
  const int wn   = w >> 1;            // n-eighth (32 cols)

  const int bid  = blockIdx.x;        // 512
  const int kid  = bid & 1;           // adjacent split-K partners
  const int mb   = bid >> 1;          // 0..255
  const int row0 = mb * 64;
  const int cs   = kid * CPB, c1 = cs + CPB;   // cs % 4 == 0

  f32x4 acc[2][2];
#pragma unroll
  for (int i = 0; i < 2; ++i)
#pragma unroll
    for (int j = 0; j < 2; ++j)
      acc[i][j] = (f32x4){0.f, 0.f, 0.f, 0.f};

  // builders: quarter q handles chunks with c%4==q; 256 threads cover
  // 64 rows x 4 16B-slots (spline: 1 feature/slot; base: 8 feats/slot).
  const int q    = tid >> 8;          // 0..3
  const int loc  = tid & 255;
  const int brow = loc >> 2;          // 0..63
  const int bq   = loc & 3;           // 16B slot 0..3
  const int a_wr = brow * 32 + ((bq ^ ((brow >> 1) & 3)) * 8);

  // fragment read offsets (u16 idx within one buffer), 2-way swizzle
  const int lm = lane & 15;
  const int kg = lane >> 4;           // 16B chunk (k = kg*8..+7)
  int a_off[2], b_off[2];
#pragma unroll
  for (int i = 0; i < 2; ++i) {
    int ra = wm * 32 + i * 16 + lm;
    a_off[i] = ra * 32 + ((kg ^ ((ra >> 1) & 3)) * 8);
  }
#pragma unroll
  for (int j = 0; j < 2; ++j) {
    int rb = wn * 32 + j * 16 + lm;
    b_off[j] = rb * 32 + ((kg ^ ((rb >> 1) & 3)) * 8);
  }

  // B staging: 1024 thr x 16B = 16KB chunk; linear LDS dest, inverse-swizzled
  // global source (both-sides-or-neither).
  const u32 stage_goff = (u32)(tid >> 2) * K_TOT + (((tid & 3) ^ ((tid >> 3) & 3)) * 8);
  const int stage_loff = tid * 8;     // u16 units

  float px;            // spline x (own quarter's chunk)
  float4 pb0, pb1;     // base x

  auto LOADX = [&](int c) {
    if ((c & 3) != q) return;
    if (c < 256) {
      px = x[(size_t)(row0 + brow) * IN_F + c * 4 + bq];
    } else {
      const float* xp = x + (size_t)(row0 + brow) * IN_F + (c - 256) * 32 + bq * 8;
      pb0 = *(const float4*)xp;
      pb1 = *(const float4*)(xp + 4);
    }
  };

  auto BUILD = [&](int c) {
    if ((c & 3) != q) return;
    uint4 v;
    if (c < 256) {
      v = basis8(px);
    } else {
      v.x = pk2(silu(pb0.x), silu(pb0.y));
      v.y = pk2(silu(pb0.z), silu(pb0.w));
      v.z = pk2(silu(pb1.x), silu(pb1.y));
      v.w = pk2(silu(pb1.z), silu(pb1.w));
    }
    *(uint4*)(As + (c & 3) * (64 * 32) + a_wr) = v;
  };

  auto STAGEB = [&](int c) {
    const u16* gp = Bp + stage_goff + c * 32;
    __builtin_amdgcn_global_load_lds((const __attribute__((address_space(1))) void*)gp,
                                     (__attribute__((address_space(3))) void*)
                                       (Bs + (c & 3) * (256 * 32) + stage_loff),
                                     16, 0, 0);
  };

  // ---- prologue: x for cs..cs+2, build them, stage them; wait chunk cs ----
  LOADX(cs); LOADX(cs + 1); LOADX(cs + 2);
  asm volatile("s_waitcnt vmcnt(0)" ::: "memory");     // x landed (no glds yet)
  BUILD(cs); BUILD(cs + 1); BUILD(cs + 2);
  STAGEB(cs); STAGEB(cs + 1); STAGEB(cs + 2);
  asm volatile("s_waitcnt vmcnt(2) lgkmcnt(0)" ::: "memory");  // cs's glds + builds done
  __builtin_amdgcn_s_barrier();

  // ---- main loop: 1 phase per BK=32 chunk, counted vmcnt, MFMA post-barrier ----
  for (int c = cs; c < c1; ++c) {
    const u16* Ab = As + (c & 3) * (64 * 32);
    const u16* Bb = Bs + (c & 3) * (256 * 32);
    short8 af[2], bf[2];
#pragma unroll
    for (int i = 0; i < 2; ++i) af[i] = *(const short8*)(Ab + a_off[i]);
#pragma unroll
    for (int j = 0; j < 2; ++j) bf[j] = *(const short8*)(Bb + b_off[j]);

    if (c + 3 < c1) STAGEB(c + 3);          // depth-3 prefetch (buf of c-1, safe)
    if (c + 2 < c1) BUILD(c + 2);           // As buf of c-2, safe
    if (c + 3 < c1) LOADX(c + 3);

    // guarantee chunk c+1's glds landed at barrier-exit (consumed next phase).
    // after glds(c+1) a thread issues <= {glds(c+2), glds(c+3), 1 xload} = 3.
    const int rem = c1 - c;
    if (rem >= 4)      asm volatile("s_waitcnt vmcnt(3) lgkmcnt(0)" ::: "memory");
    else if (rem == 3) asm volatile("s_waitcnt vmcnt(2) lgkmcnt(0)" ::: "memory");
    else               asm volatile("s_waitcnt vmcnt(0) lgkmcnt(0)" ::: "memory");
    __builtin_amdgcn_s_barrier();

    __builtin_amdgcn_s_setprio(1);
#pragma unroll
    for (int i = 0; i < 2; ++i)
#pragma unroll
      for (int j = 0; j < 2; ++j)
        acc[i][j] = __builtin_amdgcn_mfma_f32_16x16x32_bf16(af[i], bf[j], acc[i][j], 0, 0, 0);
    __builtin_amdgcn_s_setprio(0);
  }

  // ---- epilogue: C/D col=lane&15, row=(lane>>4)*4+reg; split-K=2 -> 2 atomic writers ----
  const int lc = lane & 15;
  const int lr = (lane >> 4) * 4;
#pragma unroll
  for (int i = 0; i < 2; ++i) {
#pragma unroll
    for (int j = 0; j < 2; ++j) {
      int gr = row0 + wm * 32 + i * 16 + lr;
      int gc = wn * 32 + j * 16 + lc;
      float* po = out + (size_t)gr * N_COLS + gc;
#pragma unroll
      for (int r = 0; r < 4; ++r)
        unsafeAtomicAdd(po + (size_t)r * N_COLS, acc[i][j][r]);
    }
  }
}

extern "C" void kernel_launch(void* const* d_in, const int* in_sizes, int n_in,
                              void* d_out, int out_size, void* d_ws, size_t ws_size,
                              hipStream_t stream) {
  const float* x  = (const float*)d_in[0];   // 16384 x 1024
  const float* bw = (const float*)d_in[1];   // 256 x 1024
  const float* sw = (const float*)d_in[2];   // 256 x 8192
  float* out = (float*)d_out;                // 16384 x 256 f32
  u16* Bp = (u16*)d_ws;                      // 256 x 9216 bf16 = 4.5 MB

  hipMemsetAsync(d_out, 0, (size_t)M_ROWS * N_COLS * sizeof(float), stream);

  dim3 pgrid(K_TOT / 4 / 256, N_COLS);       // (9, 256)
  pack_weights<<<pgrid, 256, 0, stream>>>(bw, sw, Bp);

  kan_gemm<<<512, 1024, 0, stream>>>(x, Bp, out);
}